// Round 11
// baseline (498.622 us; speedup 1.0000x reference)
//
#include <hip/hip_runtime.h>
#include <hip/hip_bf16.h>

#define NXC 440
#define NYC 500
#define GCELLS (NXC * NYC)            // 220000 (NZ = 1)
#define NWORDS 6875                   // GCELLS/32 exactly
#define MAXV 40000
#define MAXP 32
#define TPAD 16                       // ticket stride: 1 counter / 64B line
#define GRID 512
#define BLK 256
#define NTHR (GRID * BLK)             // 131072
#define PPT 16                        // reg-cached points/thread (n<=2,097,152)
#define WPB ((NWORDS + GRID - 1) / GRID)   // 14 words per block (scan slices)
#define ORCH 16                       // OR-reduce chunks per word (512/32)

// Expected outputs are bf16-quantized but stored as fp32: round-trip.
__device__ __forceinline__ float bf16r(float x) {
    return __bfloat162float(__float2bfloat16(x));
}

// Cell from coords, matching numpy fp32 semantics. Invalid -> -1.
__device__ __forceinline__ int cell_from(float x, float y, float z) {
    bool valid = (x >= 0.0f) && (x < 70.4f) &&
                 (y >= -40.0f) && (y < 40.0f) &&
                 (z >= -3.0f) && (z < 1.0f);
    if (!valid) return -1;
    int cx = (int)floorf(x / 0.16f);
    int cy = (int)floorf((y + 40.0f) / 0.16f);
    cx = min(max(cx, 0), NXC - 1);
    cy = min(max(cy, 0), NYC - 1);
    return cy * NXC + cx;
}

__device__ __forceinline__ int point_cell(const float* p) {
    return cell_from(p[0], p[1], p[2]);
}

// Single-use grid barrier (one counter per phase, pre-zeroed by memsetAsync).
// Release/acquire via agent-scope fences; blocks are co-resident by design:
// __launch_bounds__(256,4) => VGPR<=128 => >=4 blocks/CU; LDS 28.6KB => 5/CU;
// 512 blocks << 1024 capacity.
__device__ __forceinline__ void gbar(int* cnt) {
    __syncthreads();
    if (threadIdx.x == 0) {
        __threadfence();   // release: drain + make prior writes visible device-wide
        __hip_atomic_fetch_add(cnt, 1, __ATOMIC_ACQ_REL, __HIP_MEMORY_SCOPE_AGENT);
        while (__hip_atomic_load(cnt, __ATOMIC_ACQUIRE, __HIP_MEMORY_SCOPE_AGENT) < GRID) {}
        __threadfence();   // acquire: invalidate stale cached lines
    }
    __syncthreads();
}

__global__ __launch_bounds__(BLK, 4) void k_fused(
        const float* __restrict__ pts, int n, int S, int* bar,
        unsigned* bitmaps, unsigned* occ, int* wpre, int* partials,
        int* vox2cell, int* ticket, int* seg,
        float* out_vox, float* out_coords, float* out_np) {
    __shared__ unsigned bm[NWORDS];   // 27.5 KB
    __shared__ int sp[WPB];
    __shared__ int red[BLK];
    const int b = blockIdx.x, t = threadIdx.x;
    const int gid = b * BLK + t;

    // ---- P1: cells -> registers + LDS occupancy bitmap; zero-init globals ----
    for (int w = t; w < NWORDS; w += BLK) bm[w] = 0u;
    __syncthreads();
    int cid[PPT];
    #pragma unroll
    for (int k = 0; k < PPT; ++k) {
        int i = gid + k * NTHR;
        int c = -1;
        if (i < n) c = point_cell(pts + (size_t)i * 5);
        cid[k] = c;
        if (c >= 0) {
            int wi = c >> 5; unsigned mk = 1u << (c & 31);
            if (!(bm[wi] & mk)) atomicOr(&bm[wi], mk);   // read-first: ~89% skip
        }
    }
    for (int i = gid + PPT * NTHR; i < n; i += NTHR) {   // safety tail
        int c = point_cell(pts + (size_t)i * 5);
        if (c >= 0) {
            int wi = c >> 5; unsigned mk = 1u << (c & 31);
            if (!(bm[wi] & mk)) atomicOr(&bm[wi], mk);
        }
    }
    for (int idx = gid; idx < NWORDS; idx += NTHR) occ[idx] = 0u;
    for (int idx = gid; idx < MAXV * TPAD; idx += NTHR) ticket[idx] = 0;
    for (int idx = gid; idx < MAXV; idx += NTHR) vox2cell[idx] = -1;
    __syncthreads();
    {
        unsigned* dst = bitmaps + (size_t)b * NWORDS;
        for (int w = t; w < NWORDS; w += BLK) dst[w] = bm[w];
    }
    gbar(bar + 0);

    // ---- P2: 16-way parallel OR-reduce of 512 bitmaps -> occ ----
    if (gid < NWORDS * ORCH) {
        int w = gid % NWORDS, chunk = gid / NWORDS;
        const unsigned* src = bitmaps + (size_t)(chunk * 32) * NWORDS + w;
        unsigned o = 0u;
        #pragma unroll
        for (int g2 = 0; g2 < 32; ++g2) o |= src[(size_t)g2 * NWORDS];
        if (o) atomicOr(&occ[w], o);
    }
    gbar(bar + 1);

    // ---- P3a: per-block popcount partials over WPB-word slice ----
    const int w0 = b * WPB;
    if (t < WPB && w0 + t < NWORDS) sp[t] = __popc(occ[w0 + t]);
    __syncthreads();
    if (t == 0) {
        int s = 0;
        for (int j = 0; j < WPB; ++j) if (w0 + j < NWORDS) s += sp[j];
        partials[b] = s;
    }
    gbar(bar + 2);

    // ---- P3b: each block independently prefixes partials; emit wpre+vox2cell ----
    {
        int pv = 0;
        for (int j = t; j < b; j += BLK) pv += partials[j];
        red[t] = pv;
        __syncthreads();
        for (int d = BLK / 2; d > 0; d >>= 1) {
            if (t < d) red[t] += red[t + d];
            __syncthreads();
        }
        int bpre = red[0];
        if (t < WPB && w0 + t < NWORDS) {
            int lpre = 0;
            for (int j = 0; j < t; ++j) if (w0 + j < NWORDS) lpre += sp[j];
            int vid = bpre + lpre;
            int w = w0 + t;
            wpre[w] = vid;
            unsigned m = occ[w];
            while (m && vid < MAXV) {
                int bit = __ffs(m) - 1;
                m &= m - 1u;
                vox2cell[vid] = w * 32 + bit;
                ++vid;
            }
        }
    }
    gbar(bar + 3);

    // ---- P4: scatter (reg-cached cells, padded tickets) ----
    #pragma unroll
    for (int k = 0; k < PPT; ++k) {
        int i = gid + k * NTHR;
        int c = cid[k];
        if (i < n && c >= 0) {
            int w = c >> 5, bit = c & 31;
            int vid = wpre[w] + __popc(occ[w] & ((1u << bit) - 1u));
            if (vid < MAXV) {
                int tk = atomicAdd(&ticket[(size_t)vid * TPAD], 1);
                if (tk < S) seg[(size_t)vid * S + tk] = i;
            }
        }
    }
    for (int i = gid + PPT * NTHR; i < n; i += NTHR) {   // safety tail
        int c = point_cell(pts + (size_t)i * 5);
        if (c >= 0) {
            int w = c >> 5, bit = c & 31;
            int vid = wpre[w] + __popc(occ[w] & ((1u << bit) - 1u));
            if (vid < MAXV) {
                int tk = atomicAdd(&ticket[(size_t)vid * TPAD], 1);
                if (tk < S) seg[(size_t)vid * S + tk] = i;
            }
        }
    }
    gbar(bar + 4);

    // ---- P5: fill — one wave per voxel; rank via shfl, route via ds_permute ----
    const int wv = gid >> 6;          // global wave id, 0..2047
    const int lane = t & 63;
    for (int v = wv; v < MAXV; v += NTHR / 64) {
        int ntot = ticket[(size_t)v * TPAD];
        int nn = min(ntot, S);        // S>=32; P(count>S) ~ 0
        int m = min(nn, MAXP);
        int myidx = (lane < nn) ? seg[(size_t)v * S + lane] : 0x7fffffff;
        int rank = 0;
        for (int j = 0; j < nn; ++j) {
            int ej = __shfl(myidx, j, 64);
            rank += (ej < myidx) ? 1 : 0;
        }
        // push myidx to lane 'rank' (padding lanes collide on lane nn: unread)
        int val = __builtin_amdgcn_ds_permute(rank << 2, myidx);
        if (lane < MAXP) {
            float* dst = out_vox + ((size_t)v * MAXP + lane) * 5;
            if (lane < m) {
                const float* src = pts + (size_t)val * 5;
                #pragma unroll
                for (int k = 0; k < 5; ++k) dst[k] = bf16r(src[k]);
            } else {
                #pragma unroll
                for (int k = 0; k < 5; ++k) dst[k] = 0.0f;
            }
        } else if (lane == 32) {
            int cell = vox2cell[v];
            float* oc = out_coords + (size_t)v * 3;
            if (cell >= 0) {
                int cy = cell / NXC, cx = cell - cy * NXC;
                oc[0] = 0.0f;
                oc[1] = bf16r((float)cy);
                oc[2] = bf16r((float)cx);
            } else {
                oc[0] = 0.0f; oc[1] = 0.0f; oc[2] = 0.0f;
            }
        } else if (lane == 33) {
            out_np[v] = bf16r((float)m);
        }
    }
}

extern "C" void kernel_launch(void* const* d_in, const int* in_sizes, int n_in,
                              void* d_out, int out_size, void* d_ws, size_t ws_size,
                              hipStream_t stream) {
    const float* pts = (const float*)d_in[0];
    int n = in_sizes[0] / 5;

    float* out = (float*)d_out;   // fp32 storage, bf16-precision values
    float* out_vox    = out;                                   // MAXV*32*5
    float* out_coords = out + (size_t)MAXV * MAXP * 5;         // MAXV*3
    float* out_np     = out_coords + (size_t)MAXV * 3;         // MAXV

    // Segment capacity: prefer 64 (observed ws ~256 MiB; need ~27 MB).
    int S = 64;
    {
        auto need = [&](int s) {
            return (16 + (size_t)GRID * NWORDS + 2 * (size_t)NWORDS + GRID + MAXV
                    + (size_t)MAXV * TPAD + (size_t)MAXV * s) * sizeof(int);
        };
        if (need(64) > ws_size) S = 32;
    }

    int* ws = (int*)d_ws;
    int* bar          = ws;                                    // 16 (5 used)
    unsigned* bitmaps = (unsigned*)(ws + 16);                  // GRID*NWORDS
    unsigned* occ     = bitmaps + (size_t)GRID * NWORDS;       // NWORDS
    int* wpre         = (int*)(occ + NWORDS);                  // NWORDS
    int* partials     = wpre + NWORDS;                         // GRID
    int* vox2cell     = partials + GRID;                       // MAXV
    int* ticket       = vox2cell + MAXV;                       // MAXV*TPAD
    int* seg          = ticket + (size_t)MAXV * TPAD;          // MAXV*S

    // Zero the grid-barrier counters (ws is poisoned 0xAA before every launch).
    hipMemsetAsync(bar, 0, 16 * sizeof(int), stream);
    k_fused<<<GRID, BLK, 0, stream>>>(pts, n, S, bar, bitmaps, occ, wpre,
                                      partials, vox2cell, ticket, seg,
                                      out_vox, out_coords, out_np);
}

// Round 12
// 149.539 us; speedup vs baseline: 3.3344x; 3.3344x over previous
//
#include <hip/hip_runtime.h>
#include <hip/hip_bf16.h>

#define NXC 440
#define NYC 500
#define GCELLS (NXC * NYC)            // 220000 (NZ = 1)
#define NWORDS ((GCELLS + 31) / 32)   // 6875 bitmap words
#define MAXV 40000
#define MAXP 32
#define SCANB ((NWORDS + 255) / 256)  // 27 blocks for word-sliced kernels
#define GPB 16                        // bitmaps OR'd per k_orred block
#define TPAD 16                       // ticket stride (ints): 1 counter / 64B line

// Expected outputs are bf16-quantized but stored as fp32: round-trip.
__device__ __forceinline__ float bf16r(float x) {
    return __bfloat162float(__float2bfloat16(x));
}

// Linear cell index exactly as the numpy reference (fp32 ops). Invalid -> -1.
__device__ __forceinline__ int point_cell(const float* p) {
    float x = p[0], y = p[1], z = p[2];
    bool valid = (x >= 0.0f) && (x < 70.4f) &&
                 (y >= -40.0f) && (y < 40.0f) &&
                 (z >= -3.0f) && (z < 1.0f);
    if (!valid) return -1;
    int cx = (int)floorf(x / 0.16f);
    int cy = (int)floorf((y + 40.0f) / 0.16f);
    // z in [-3,1) -> cz == 0 always (NZ = 1)
    cx = min(max(cx, 0), NXC - 1);
    cy = min(max(cy, 0), NYC - 1);
    return cy * NXC + cx;
}

// Pass 1 (r7 k_cell + folded zero-init): LDS occupancy bitmap + cellid cache.
__global__ __launch_bounds__(256) void k_cell(const float* pts, int* cellid,
                                              unsigned* bitmaps, unsigned* occ,
                                              int* ticket, int n, int G) {
    __shared__ unsigned bm[NWORDS];   // 27.5 KB
    for (int w = threadIdx.x; w < NWORDS; w += 256) bm[w] = 0u;
    __syncthreads();
    int tid = blockIdx.x * 256 + threadIdx.x;
    int stride = G * 256;
    for (int i = tid; i < n; i += stride) {
        int cell = point_cell(pts + (size_t)i * 5);
        if (cellid) cellid[i] = cell;
        if (cell >= 0) atomicOr(&bm[cell >> 5], 1u << (cell & 31));
    }
    // zero-init for later kernels (stream order guarantees visibility)
    for (int idx = tid; idx < NWORDS; idx += stride) occ[idx] = 0u;
    for (int idx = tid; idx < MAXV * TPAD; idx += stride) ticket[idx] = 0;
    __syncthreads();
    unsigned* dst = bitmaps + (size_t)blockIdx.x * NWORDS;
    for (int w = threadIdx.x; w < NWORDS; w += 256) dst[w] = bm[w];
}

// Parallel OR-reduce: block (bx, by) ORs bitmaps [by*GPB, (by+1)*GPB) over its
// 256-word slice, one atomicOr per word into occ (zeroed in k_cell).
__global__ __launch_bounds__(256) void k_orred(const unsigned* bitmaps, unsigned* occ) {
    int w = blockIdx.x * 256 + threadIdx.x;
    if (w >= NWORDS) return;
    const unsigned* src = bitmaps + (size_t)blockIdx.y * GPB * NWORDS + w;
    unsigned o = 0u;
    #pragma unroll
    for (int g = 0; g < GPB; ++g) o |= src[(size_t)g * NWORDS];
    if (o) atomicOr(&occ[w], o);
}

// Per-SCANB-block popcount partials of the final occ bitmap.
__global__ __launch_bounds__(256) void k_partials(const unsigned* occ, int* partials) {
    int w = blockIdx.x * 256 + threadIdx.x;
    __shared__ int s[256];
    s[threadIdx.x] = (w < NWORDS) ? __popc(occ[w]) : 0;
    __syncthreads();
    for (int d = 128; d > 0; d >>= 1) {
        if (threadIdx.x < d) s[threadIdx.x] += s[threadIdx.x + d];
        __syncthreads();
    }
    if (threadIdx.x == 0) partials[blockIdx.x] = s[0];
}

// Word-level exclusive scan of popcounts -> wordprefix; emit coords for kept voxels.
__global__ __launch_bounds__(256) void k_scan(const unsigned* occ, const int* partials,
                                              int* wpre, float* out_coords) {
    int b = blockIdx.x, t = threadIdx.x;
    int w = b * 256 + t;
    unsigned o = (w < NWORDS) ? occ[w] : 0u;
    int c = __popc(o);
    __shared__ int s[256];
    s[t] = c;
    __syncthreads();
    for (int d = 1; d < 256; d <<= 1) {
        int v = (t >= d) ? s[t - d] : 0;
        __syncthreads();
        s[t] += v;
        __syncthreads();
    }
    int base = 0;
    for (int g = 0; g < b; ++g) base += partials[g];   // <=26 cached loads
    int vid = base + (s[t] - c);
    if (w < NWORDS) {
        wpre[w] = vid;
        if (vid < MAXV) {
            unsigned m = o;
            while (m) {
                int bit = __ffs(m) - 1;
                m &= m - 1u;
                if (vid < MAXV) {
                    int cell = w * 32 + bit;
                    int cy = cell / NXC, cx = cell - cy * NXC;
                    float* oc = out_coords + (size_t)vid * 3;
                    oc[0] = 0.0f;
                    oc[1] = bf16r((float)cy);
                    oc[2] = bf16r((float)cx);
                }
                ++vid;
            }
        }
    }
}

__device__ __forceinline__ void scat1(int cell, int i, const unsigned* occ,
                                      const int* wpre, int* ticket, int* seg, int S) {
    if (cell < 0) return;
    int w = cell >> 5, b = cell & 31;
    int vid = wpre[w] + __popc(occ[w] & ((1u << b) - 1u));
    if (vid >= MAXV) return;
    int t = atomicAdd(&ticket[(size_t)vid * TPAD], 1);
    if (t < S) seg[(size_t)vid * S + t] = i;
}

// Scatter point indices into fixed-stride per-voxel segments, 4 pts/thread
// via int4 cellid loads (4 independent lookup->atomic chains per thread).
__global__ __launch_bounds__(256) void k_scatter(const float* pts, const int* cellid,
                                                 const unsigned* occ, const int* wpre,
                                                 int* ticket, int* seg, int S, int n) {
    int g = blockIdx.x * 256 + threadIdx.x;
    int n4 = n >> 2;
    if (cellid) {
        if (g < n4) {
            int4 cc = ((const int4*)cellid)[g];
            int i0 = g * 4;
            scat1(cc.x, i0 + 0, occ, wpre, ticket, seg, S);
            scat1(cc.y, i0 + 1, occ, wpre, ticket, seg, S);
            scat1(cc.z, i0 + 2, occ, wpre, ticket, seg, S);
            scat1(cc.w, i0 + 3, occ, wpre, ticket, seg, S);
        }
        if (g == 0) {
            for (int i = n4 * 4; i < n; ++i)
                scat1(cellid[i], i, occ, wpre, ticket, seg, S);
        }
    } else {
        if (g < n) scat1(point_cell(pts + (size_t)g * 5), g, occ, wpre, ticket, seg, S);
    }
}

// One wave per voxel: rank by original index (stable), gather feats, write ALL
// 32 slots (zeros for empty ranks) + num_points. No output memset needed.
__global__ __launch_bounds__(256) void k_fill(const float* pts, const int* ticket,
                                              const int* seg, int S,
                                              float* out_vox, float* out_np) {
    __shared__ int slot[4][MAXP];
    int wave = threadIdx.x >> 6, lane = threadIdx.x & 63;
    int v = blockIdx.x * 4 + wave;     // MAXV % 4 == 0 -> always in range
    int ntot = ticket[(size_t)v * TPAD];
    int nn = min(ntot, S);             // S >= 32; P(cell count > S) ~ 0
    int m = min(nn, MAXP);
    int myidx = (lane < nn) ? seg[(size_t)v * S + lane] : 0x7fffffff;
    int rank = 0;
    for (int j = 0; j < nn; ++j) {
        int ej = __shfl(myidx, j, 64);
        rank += (ej < myidx) ? 1 : 0;
    }
    if (lane < nn && rank < MAXP) slot[wave][rank] = myidx;
    __syncthreads();   // order LDS scatter before readback (all threads reach)
    if (lane < MAXP) {
        float* dst = out_vox + ((size_t)v * MAXP + lane) * 5;
        if (lane < m) {
            const float* src = pts + (size_t)slot[wave][lane] * 5;
            #pragma unroll
            for (int k = 0; k < 5; ++k) dst[k] = bf16r(src[k]);
        } else {
            #pragma unroll
            for (int k = 0; k < 5; ++k) dst[k] = 0.0f;
        }
    }
    if (lane == 0) out_np[v] = bf16r((float)m);
}

extern "C" void kernel_launch(void* const* d_in, const int* in_sizes, int n_in,
                              void* d_out, int out_size, void* d_ws, size_t ws_size,
                              hipStream_t stream) {
    const float* pts = (const float*)d_in[0];
    int n = in_sizes[0] / 5;

    float* out = (float*)d_out;   // fp32 storage, bf16-precision values
    float* out_vox    = out;                                   // MAXV*32*5
    float* out_coords = out + (size_t)MAXV * MAXP * 5;         // MAXV*3
    float* out_np     = out_coords + (size_t)MAXV * 3;         // MAXV

    // ws ints: cellid[n]? + bitmaps[G*NWORDS] + occ[NWORDS] + ticket[MAXV*TPAD]
    //          + wpre[NWORDS] + partials[32] + seg[MAXV*S]
    const size_t fixed_ints = 2 * (size_t)NWORDS + 32 + (size_t)MAXV * TPAD;
    int G = 64, S = 32; bool use_cid = false;
    {
        auto fits = [&](int g, int s, bool cid) {
            size_t ints = fixed_ints + (size_t)g * NWORDS + (size_t)MAXV * s
                        + (cid ? (size_t)n : 0);
            return ints * sizeof(int) <= ws_size;
        };
        struct Cfg { int g, s; bool cid; };
        const Cfg cfgs[] = {
            {512, 64, true},   // k_cell at 2 blocks/CU (LDS 27.5KB)
            {256, 64, true}, {256, 48, true}, {128, 48, true},
            {128, 40, false}, {64, 32, false}, {32, 32, false},
        };
        for (const Cfg& c : cfgs) {
            if (fits(c.g, c.s, c.cid)) { G = c.g; S = c.s; use_cid = c.cid; break; }
        }
    }

    int* ws = (int*)d_ws;
    int* cellid        = use_cid ? ws : nullptr;                       // n (optional)
    unsigned* bitmaps  = (unsigned*)(ws + (use_cid ? (size_t)n : 0));  // G*NWORDS
    unsigned* occ      = bitmaps + (size_t)G * NWORDS;                 // NWORDS (zeroed in k_cell)
    int* ticket        = (int*)(occ + NWORDS);                         // MAXV*TPAD (zeroed in k_cell)
    int* wpre          = ticket + (size_t)MAXV * TPAD;                 // NWORDS
    int* partials      = wpre + NWORDS;                                // 32
    int* seg           = partials + 32;                                // MAXV * S

    int nb  = (n + 255) / 256;
    int nb4 = (n / 4 + 255) / 256;
    k_cell<<<G, 256, 0, stream>>>(pts, cellid, bitmaps, occ, ticket, n, G);
    k_orred<<<dim3(SCANB, G / GPB), 256, 0, stream>>>(bitmaps, occ);
    k_partials<<<SCANB, 256, 0, stream>>>(occ, partials);
    k_scan<<<SCANB, 256, 0, stream>>>(occ, partials, wpre, out_coords);
    k_scatter<<<(use_cid ? nb4 : nb), 256, 0, stream>>>(pts, cellid, occ, wpre,
                                                        ticket, seg, S, n);
    k_fill<<<(MAXV + 3) / 4, 256, 0, stream>>>(pts, ticket, seg, S, out_vox, out_np);
}

// Round 13
// 149.000 us; speedup vs baseline: 3.3465x; 1.0036x over previous
//
#include <hip/hip_runtime.h>
#include <hip/hip_bf16.h>

#define NXC 440
#define NYC 500
#define GCELLS (NXC * NYC)            // 220000 (NZ = 1)
#define NWORDS ((GCELLS + 31) / 32)   // 6875 bitmap words
#define MAXV 40000
#define MAXP 32
#define SCANB ((NWORDS + 255) / 256)  // 27 blocks for word-sliced kernels
#define GPB 16                        // bitmaps OR'd per k_orred block
#define TPAD 16                       // ticket stride (ints): 1 counter / 64B line

// Expected outputs are bf16-quantized but stored as fp32: round-trip.
__device__ __forceinline__ float bf16r(float x) {
    return __bfloat162float(__float2bfloat16(x));
}

// Linear cell index exactly as the numpy reference (fp32 ops). Invalid -> -1.
__device__ __forceinline__ int point_cell(const float* p) {
    float x = p[0], y = p[1], z = p[2];
    bool valid = (x >= 0.0f) && (x < 70.4f) &&
                 (y >= -40.0f) && (y < 40.0f) &&
                 (z >= -3.0f) && (z < 1.0f);
    if (!valid) return -1;
    int cx = (int)floorf(x / 0.16f);
    int cy = (int)floorf((y + 40.0f) / 0.16f);
    // z in [-3,1) -> cz == 0 always (NZ = 1)
    cx = min(max(cx, 0), NXC - 1);
    cy = min(max(cy, 0), NYC - 1);
    return cy * NXC + cx;
}

// Pass 1: LDS occupancy bitmap + cellid cache + folded zero-init.
__global__ __launch_bounds__(256) void k_cell(const float* pts, int* cellid,
                                              unsigned* bitmaps, unsigned* occ,
                                              int* ticket, int n, int G) {
    __shared__ unsigned bm[NWORDS];   // 27.5 KB
    for (int w = threadIdx.x; w < NWORDS; w += 256) bm[w] = 0u;
    __syncthreads();
    int tid = blockIdx.x * 256 + threadIdx.x;
    int stride = G * 256;
    for (int i = tid; i < n; i += stride) {
        int cell = point_cell(pts + (size_t)i * 5);
        if (cellid) cellid[i] = cell;
        if (cell >= 0) atomicOr(&bm[cell >> 5], 1u << (cell & 31));
    }
    // zero-init for later kernels (stream order guarantees visibility)
    for (int idx = tid; idx < NWORDS; idx += stride) occ[idx] = 0u;
    for (int idx = tid; idx < MAXV * TPAD; idx += stride) ticket[idx] = 0;
    __syncthreads();
    unsigned* dst = bitmaps + (size_t)blockIdx.x * NWORDS;
    for (int w = threadIdx.x; w < NWORDS; w += 256) dst[w] = bm[w];
}

// Parallel OR-reduce: block (bx, by) ORs bitmaps [by*GPB, (by+1)*GPB) over its
// 256-word slice, one atomicOr per word into occ (zeroed in k_cell).
__global__ __launch_bounds__(256) void k_orred(const unsigned* bitmaps, unsigned* occ) {
    int w = blockIdx.x * 256 + threadIdx.x;
    if (w >= NWORDS) return;
    const unsigned* src = bitmaps + (size_t)blockIdx.y * GPB * NWORDS + w;
    unsigned o = 0u;
    #pragma unroll
    for (int g = 0; g < GPB; ++g) o |= src[(size_t)g * NWORDS];
    if (o) atomicOr(&occ[w], o);
}

// Word-level exclusive scan (self-computed cross-block base: occ is 27.5 KB,
// L2-resident) -> wordprefix; emit coords for kept voxels.
__global__ __launch_bounds__(256) void k_scan(const unsigned* occ,
                                              int* wpre, float* out_coords) {
    int b = blockIdx.x, t = threadIdx.x;
    // cross-block base: popcount of all words before this block's slice
    __shared__ int sb[256];
    int pre = 0;
    for (int w = t; w < b * 256; w += 256) pre += __popc(occ[w]);
    sb[t] = pre;
    __syncthreads();
    for (int d = 128; d > 0; d >>= 1) {
        if (t < d) sb[t] += sb[t + d];
        __syncthreads();
    }
    int base = sb[0];
    // intra-block scan over this slice
    int w = b * 256 + t;
    unsigned o = (w < NWORDS) ? occ[w] : 0u;
    int c = __popc(o);
    __shared__ int s[256];
    s[t] = c;
    __syncthreads();
    for (int d = 1; d < 256; d <<= 1) {
        int v = (t >= d) ? s[t - d] : 0;
        __syncthreads();
        s[t] += v;
        __syncthreads();
    }
    int vid = base + (s[t] - c);
    if (w < NWORDS) {
        wpre[w] = vid;
        if (vid < MAXV) {
            unsigned m = o;
            while (m) {
                int bit = __ffs(m) - 1;
                m &= m - 1u;
                if (vid < MAXV) {
                    int cell = w * 32 + bit;
                    int cy = cell / NXC, cx = cell - cy * NXC;
                    float* oc = out_coords + (size_t)vid * 3;
                    oc[0] = 0.0f;
                    oc[1] = bf16r((float)cy);
                    oc[2] = bf16r((float)cx);
                }
                ++vid;
            }
        }
    }
}

__device__ __forceinline__ void scat1(int cell, int i, const unsigned* occ,
                                      const int* wpre, int* ticket, int* seg, int S) {
    if (cell < 0) return;
    int w = cell >> 5, b = cell & 31;
    int vid = wpre[w] + __popc(occ[w] & ((1u << b) - 1u));
    if (vid >= MAXV) return;
    int t = atomicAdd(&ticket[(size_t)vid * TPAD], 1);
    if (t < S) seg[(size_t)vid * S + t] = i;
}

// Scatter point indices into fixed-stride per-voxel segments, 8 pts/thread
// via 2x int4 cellid loads (8 independent lookup->atomic chains: latency ILP).
__global__ __launch_bounds__(256) void k_scatter(const float* pts, const int* cellid,
                                                 const unsigned* occ, const int* wpre,
                                                 int* ticket, int* seg, int S, int n) {
    int g = blockIdx.x * 256 + threadIdx.x;
    int n8 = n >> 3;
    if (cellid) {
        if (g < n8) {
            const int4* c4 = (const int4*)cellid;
            int4 ca = c4[g * 2], cb = c4[g * 2 + 1];
            int i0 = g * 8;
            scat1(ca.x, i0 + 0, occ, wpre, ticket, seg, S);
            scat1(ca.y, i0 + 1, occ, wpre, ticket, seg, S);
            scat1(ca.z, i0 + 2, occ, wpre, ticket, seg, S);
            scat1(ca.w, i0 + 3, occ, wpre, ticket, seg, S);
            scat1(cb.x, i0 + 4, occ, wpre, ticket, seg, S);
            scat1(cb.y, i0 + 5, occ, wpre, ticket, seg, S);
            scat1(cb.z, i0 + 6, occ, wpre, ticket, seg, S);
            scat1(cb.w, i0 + 7, occ, wpre, ticket, seg, S);
        }
        if (g == 0) {
            for (int i = n8 * 8; i < n; ++i)
                scat1(cellid[i], i, occ, wpre, ticket, seg, S);
        }
    } else {
        if (g < n) scat1(point_cell(pts + (size_t)g * 5), g, occ, wpre, ticket, seg, S);
    }
}

// One wave per voxel: rank by original index (stable), gather feats, write ALL
// 32 slots (zeros for empty ranks) + num_points. No output memset needed.
__global__ __launch_bounds__(256) void k_fill(const float* pts, const int* ticket,
                                              const int* seg, int S,
                                              float* out_vox, float* out_np) {
    __shared__ int slot[4][MAXP];
    int wave = threadIdx.x >> 6, lane = threadIdx.x & 63;
    int v = blockIdx.x * 4 + wave;     // MAXV % 4 == 0 -> always in range
    int ntot = ticket[(size_t)v * TPAD];
    int nn = min(ntot, S);             // S >= 32; P(cell count > S) ~ 0
    int m = min(nn, MAXP);
    int myidx = (lane < nn) ? seg[(size_t)v * S + lane] : 0x7fffffff;
    int rank = 0;
    for (int j = 0; j < nn; ++j) {
        int ej = __shfl(myidx, j, 64);
        rank += (ej < myidx) ? 1 : 0;
    }
    if (lane < nn && rank < MAXP) slot[wave][rank] = myidx;
    __syncthreads();   // order LDS scatter before readback (all threads reach)
    if (lane < MAXP) {
        float* dst = out_vox + ((size_t)v * MAXP + lane) * 5;
        if (lane < m) {
            const float* src = pts + (size_t)slot[wave][lane] * 5;
            #pragma unroll
            for (int k = 0; k < 5; ++k) dst[k] = bf16r(src[k]);
        } else {
            #pragma unroll
            for (int k = 0; k < 5; ++k) dst[k] = 0.0f;
        }
    }
    if (lane == 0) out_np[v] = bf16r((float)m);
}

extern "C" void kernel_launch(void* const* d_in, const int* in_sizes, int n_in,
                              void* d_out, int out_size, void* d_ws, size_t ws_size,
                              hipStream_t stream) {
    const float* pts = (const float*)d_in[0];
    int n = in_sizes[0] / 5;

    float* out = (float*)d_out;   // fp32 storage, bf16-precision values
    float* out_vox    = out;                                   // MAXV*32*5
    float* out_coords = out + (size_t)MAXV * MAXP * 5;         // MAXV*3
    float* out_np     = out_coords + (size_t)MAXV * 3;         // MAXV

    // ws ints: cellid[n]? + bitmaps[G*NWORDS] + occ[NWORDS] + ticket[MAXV*TPAD]
    //          + wpre[NWORDS] + seg[MAXV*S]
    const size_t fixed_ints = 2 * (size_t)NWORDS + (size_t)MAXV * TPAD;
    int G = 64, S = 32; bool use_cid = false;
    {
        auto fits = [&](int g, int s, bool cid) {
            size_t ints = fixed_ints + (size_t)g * NWORDS + (size_t)MAXV * s
                        + (cid ? (size_t)n : 0);
            return ints * sizeof(int) <= ws_size;
        };
        struct Cfg { int g, s; bool cid; };
        const Cfg cfgs[] = {
            {512, 64, true},   // k_cell at 2 blocks/CU (LDS 27.5KB)
            {256, 64, true}, {256, 48, true}, {128, 48, true},
            {128, 40, false}, {64, 32, false}, {32, 32, false},
        };
        for (const Cfg& c : cfgs) {
            if (fits(c.g, c.s, c.cid)) { G = c.g; S = c.s; use_cid = c.cid; break; }
        }
    }

    int* ws = (int*)d_ws;
    int* cellid        = use_cid ? ws : nullptr;                       // n (optional)
    unsigned* bitmaps  = (unsigned*)(ws + (use_cid ? (size_t)n : 0));  // G*NWORDS
    unsigned* occ      = bitmaps + (size_t)G * NWORDS;                 // NWORDS (zeroed in k_cell)
    int* ticket        = (int*)(occ + NWORDS);                         // MAXV*TPAD (zeroed in k_cell)
    int* wpre          = ticket + (size_t)MAXV * TPAD;                 // NWORDS
    int* seg           = wpre + NWORDS;                                // MAXV * S

    int nb  = (n + 255) / 256;
    int nb8 = (n / 8 + 255) / 256;
    k_cell<<<G, 256, 0, stream>>>(pts, cellid, bitmaps, occ, ticket, n, G);
    k_orred<<<dim3(SCANB, G / GPB), 256, 0, stream>>>(bitmaps, occ);
    k_scan<<<SCANB, 256, 0, stream>>>(occ, wpre, out_coords);
    k_scatter<<<(use_cid ? nb8 : nb), 256, 0, stream>>>(pts, cellid, occ, wpre,
                                                        ticket, seg, S, n);
    k_fill<<<(MAXV + 3) / 4, 256, 0, stream>>>(pts, ticket, seg, S, out_vox, out_np);
}